// Round 2
// baseline (586.867 us; speedup 1.0000x reference)
//
#include <hip/hip_runtime.h>

// Problem dims (fixed).
#define BB 512
#define TT 1024
#define DD 64
#define HH 64
#define RR 4
#define MHH 32
#define BT (BB * TT)           // 524288
#define Y_SIZE (BB * TT * HH)  // 33554432

typedef _Float16 half8 __attribute__((ext_vector_type(8)));
typedef float f32x4 __attribute__((ext_vector_type(4)));

#define MFMA16(a, b, c) __builtin_amdgcn_mfma_f32_16x16x32_f16((a), (b), (c), 0, 0, 0)

__device__ __forceinline__ float sigm(float x) {
    return __builtin_amdgcn_rcpf(1.0f + __expf(-x));
}
__device__ __forceinline__ float tanh_(float x) {
    return 1.0f - 2.0f * __builtin_amdgcn_rcpf(1.0f + __expf(2.0f * x));
}
__device__ __forceinline__ half8 cvt8(f32x4 a, f32x4 b) {
    half8 h;
    h[0] = (_Float16)a[0]; h[1] = (_Float16)a[1];
    h[2] = (_Float16)a[2]; h[3] = (_Float16)a[3];
    h[4] = (_Float16)b[0]; h[5] = (_Float16)b[1];
    h[6] = (_Float16)b[2]; h[7] = (_Float16)b[3];
    return h;
}

// ---------------------------------------------------------------------------
// Fused LSTM + heads. 256 WGs (2 batch rows each) x 256 threads (4 waves).
//
// Step loop (16 steps/chunk): gates = [x_t ; h] @ Wcat^T via mfma 16x16x32
// with the A-replication trick (rows 0-7 = batch0, 8-15 = batch1). ALL memory
// ops in the step loop are LDS -> the per-step __syncthreads drains lgkmcnt
// only (no vmcnt(0) store/load drain on the serial chain; that was ~350
// cyc/step in R1).
//
// Chunk boundary (once per 16 steps): flush ybuf->y (coalesced), load next x
// chunk, run the 3-layer reward heads on the 32 finished y-rows (per-wave:
// 1 batch row x 2 heads, private LDS h1/h2 buffers, no extra barriers), then
// ONE vmcnt-draining barrier.
// ---------------------------------------------------------------------------
__global__ __launch_bounds__(256) void lstm_fused_kernel(
    const float* __restrict__ x, const float* __restrict__ h_init,
    const float* __restrict__ c_init, const float* __restrict__ W_ih,
    const float* __restrict__ W_hh, const float* __restrict__ b_ih,
    const float* __restrict__ b_hh,
    const float* __restrict__ W1, const float* __restrict__ b1,
    const float* __restrict__ W2, const float* __restrict__ b2,
    const float* __restrict__ W3, const float* __restrict__ b3,
    float* __restrict__ y, float* __restrict__ outs)
{
    __shared__ alignas(16) _Float16 xch[2][16][2][DD];  // x chunks f16, dbuf (8 KB)
    __shared__ alignas(16) _Float16 hst[2][2][HH];      // h stage f16, dbuf
    __shared__ alignas(16) float    ybuf[2][16][68];    // y chunk f32, pad 68 (8.7 KB)
    __shared__ alignas(16) _Float16 h1b[4][16][72];     // per-wave heads L1 out
    __shared__ alignas(16) _Float16 h2b[4][16][72];     // per-wave heads L2 out
    __shared__ alignas(16) float    w3s[128];           // W3 (4x32)

    const int tid  = threadIdx.x;
    const int wave = tid >> 6;
    const int lane = tid & 63;
    const int col  = lane & 15;
    const int quad = lane >> 4;
    const int sel  = (lane >> 3) & 1;       // batch row this lane feeds as A
    const int r_act = lane >> 5;            // batch row of this lane's gate output
    const int j    = (wave << 4) + col;     // hidden unit index [0,64)
    const bool writer = ((lane >> 4) & 1) == 0;  // quads 1,3 duplicate quads 0,2

    const int b0 = blockIdx.x * 2;

    // ---- LSTM weight fragments (resident): B[k][n] = Wcat[n][k], f16 ----
    half8 bf[4][4];
    float bias[4];
#pragma unroll
    for (int G = 0; G < 4; ++G) {
        const int n = (G << 6) + j;
        bias[G] = b_ih[n] + b_hh[n];
#pragma unroll
        for (int c = 0; c < 4; ++c) {
            const float* src = (c < 2) ? (W_ih + n * DD + c * 32 + quad * 8)
                                       : (W_hh + n * HH + (c - 2) * 32 + quad * 8);
            bf[G][c] = cvt8(*(const f32x4*)src, *(const f32x4*)(src + 4));
        }
    }

    // ---- heads weight fragments (resident, per wave) ----
    // wave = (pair, r_h): batch row r_h, heads {2*pair, 2*pair+1}
    const int pair = wave >> 1;
    const int r_h  = wave & 1;
    half8 w1f[4][2]; float bias1[4];
#pragma unroll
    for (int i = 0; i < 4; ++i) {
        const int n1 = pair * 64 + i * 16 + col;   // flat row of W1 (128x64)
        bias1[i] = b1[n1];
#pragma unroll
        for (int c = 0; c < 2; ++c) {
            const float* src = W1 + n1 * 64 + c * 32 + quad * 8;
            w1f[i][c] = cvt8(*(const f32x4*)src, *(const f32x4*)(src + 4));
        }
    }
    half8 w2f[2][2]; float bias2[2][2];
#pragma unroll
    for (int hl = 0; hl < 2; ++hl)
#pragma unroll
        for (int i2 = 0; i2 < 2; ++i2) {
            const int n2 = (pair * 2 + hl) * 32 + i2 * 16 + col;  // flat row of W2 (128x32)
            bias2[hl][i2] = b2[n2];
            const float* src = W2 + n2 * 32 + quad * 8;
            w2f[hl][i2] = cvt8(*(const f32x4*)src, *(const f32x4*)(src + 4));
        }
    if (tid < 128) w3s[tid] = W3[tid];
    const int g_l3 = pair * 2 + ((lane >> 4) & 1);  // L3 head for lanes < 32
    const float b3v = b3[g_l3];

    float c_state = c_init[j];

    // ---- init: h stage + first x chunk ----
    if (tid < 128) {
        const int rr = tid >> 6, jj = tid & 63;
        hst[0][rr][jj] = (_Float16)h_init[jj];
    }
    const int ss_ld = tid >> 4, rr_ld = (tid >> 3) & 1, j0_ld = (tid & 7) << 3;
    {
        const float* src = x + ((b0 + rr_ld) * TT + ss_ld) * DD + j0_ld;
        *(half8*)&xch[0][ss_ld][rr_ld][j0_ld] =
            cvt8(*(const f32x4*)src, *(const f32x4*)(src + 4));
    }
    __syncthreads();

    for (int ci = 0; ci < 64; ++ci) {
        const int buf = ci & 1;
        // ---------------- 16 recurrence steps: LDS-only ----------------
#pragma unroll
        for (int s = 0; s < 16; ++s) {
            const int p = s & 1;
            // h A-frags first (critical path), then x
            const _Float16* hrow = &hst[p][sel][0];
            half8 a2 = *(const half8*)(hrow + quad * 8);
            half8 a3 = *(const half8*)(hrow + 32 + quad * 8);
            const _Float16* xrow = &xch[buf][s][sel][0];
            half8 a0 = *(const half8*)(xrow + quad * 8);
            half8 a1 = *(const half8*)(xrow + 32 + quad * 8);

            f32x4 acc0 = {bias[0], bias[0], bias[0], bias[0]};
            f32x4 acc1 = {bias[1], bias[1], bias[1], bias[1]};
            f32x4 acc2 = {bias[2], bias[2], bias[2], bias[2]};
            f32x4 acc3 = {bias[3], bias[3], bias[3], bias[3]};
            acc0 = MFMA16(a0, bf[0][0], acc0); acc0 = MFMA16(a1, bf[0][1], acc0);
            acc0 = MFMA16(a2, bf[0][2], acc0); acc0 = MFMA16(a3, bf[0][3], acc0);
            acc1 = MFMA16(a0, bf[1][0], acc1); acc1 = MFMA16(a1, bf[1][1], acc1);
            acc1 = MFMA16(a2, bf[1][2], acc1); acc1 = MFMA16(a3, bf[1][3], acc1);
            acc2 = MFMA16(a0, bf[2][0], acc2); acc2 = MFMA16(a1, bf[2][1], acc2);
            acc2 = MFMA16(a2, bf[2][2], acc2); acc2 = MFMA16(a3, bf[2][3], acc2);
            acc3 = MFMA16(a0, bf[3][0], acc3); acc3 = MFMA16(a1, bf[3][1], acc3);
            acc3 = MFMA16(a2, bf[3][2], acc3); acc3 = MFMA16(a3, bf[3][3], acc3);

            const float si = sigm(acc0[0]);
            const float sf = sigm(acc1[0]);
            const float tg = tanh_(acc2[0]);
            const float so = sigm(acc3[0]);
            c_state = sf * c_state + si * tg;
            const float hv = so * tanh_(c_state);
            if (writer) {
                hst[p ^ 1][r_act][j] = (_Float16)hv;
                ybuf[r_act][s][j] = hv;           // y stays in LDS this chunk
            }
            __syncthreads();  // lgkm-only drain: no VM ops in flight here
        }

        // ---------------- chunk boundary (one vmcnt drain) ----------------
        // 1) flush ybuf -> y (coalesced dwordx4)
        {
            const int r = tid >> 7, s = (tid >> 3) & 15, j0 = (tid & 7) << 3;
            f32x4 v0 = *(const f32x4*)&ybuf[r][s][j0];
            f32x4 v1 = *(const f32x4*)&ybuf[r][s][j0 + 4];
            float* dst = y + (((long)(b0 + r) * TT + (ci << 4) + s) << 6) + j0;
            *(f32x4*)dst = v0;
            *(f32x4*)(dst + 4) = v1;
        }
        // 2) stage next x chunk (issue early; latency covered by heads below)
        if (ci + 1 < 64) {
            const float* src =
                x + ((b0 + rr_ld) * TT + ((ci + 1) << 4) + ss_ld) * DD + j0_ld;
            *(half8*)&xch[buf ^ 1][ss_ld][rr_ld][j0_ld] =
                cvt8(*(const f32x4*)src, *(const f32x4*)(src + 4));
        }
        // 3) heads on this chunk's 32 y-rows; per-wave, no barriers
        {
            const int sr = lane & 15;  // A-row = step within chunk
            const float* yb = &ybuf[r_h][sr][0];
            half8 a0 = cvt8(*(const f32x4*)(yb + quad * 8),
                            *(const f32x4*)(yb + quad * 8 + 4));
            half8 a1 = cvt8(*(const f32x4*)(yb + 32 + quad * 8),
                            *(const f32x4*)(yb + 32 + quad * 8 + 4));
            // L1: h1 = relu(y @ W1^T + b1), 4 N-tiles
#pragma unroll
            for (int i = 0; i < 4; ++i) {
                f32x4 acc = {bias1[i], bias1[i], bias1[i], bias1[i]};
                acc = MFMA16(a0, w1f[i][0], acc);
                acc = MFMA16(a1, w1f[i][1], acc);
#pragma unroll
                for (int r = 0; r < 4; ++r) {
                    float v = acc[r] > 0.0f ? acc[r] : 0.0f;
                    h1b[wave][(quad << 2) + r][i * 16 + col] = (_Float16)v;
                }
            }
            // L2: h2 = relu(h1 @ W2^T + b2), per local head (same wave: lgkm only)
            half8 ah[2];
#pragma unroll
            for (int hl = 0; hl < 2; ++hl)
                ah[hl] = *(const half8*)&h1b[wave][sr][hl * 32 + quad * 8];
#pragma unroll
            for (int hl = 0; hl < 2; ++hl)
#pragma unroll
                for (int i2 = 0; i2 < 2; ++i2) {
                    f32x4 acc = {bias2[hl][i2], bias2[hl][i2],
                                 bias2[hl][i2], bias2[hl][i2]};
                    acc = MFMA16(ah[hl], w2f[hl][i2], acc);
#pragma unroll
                    for (int r = 0; r < 4; ++r) {
                        float v = acc[r] > 0.0f ? acc[r] : 0.0f;
                        h2b[wave][(quad << 2) + r][hl * 32 + i2 * 16 + col] =
                            (_Float16)v;
                    }
                }
            // L3: dot-32 per (row, head), lanes 0..31
            if (lane < 32) {
                const int row = lane & 15, hl = lane >> 4;
                float acc = b3v;
#pragma unroll
                for (int c4 = 0; c4 < 4; ++c4) {
                    half8 v = *(const half8*)&h2b[wave][row][hl * 32 + c4 * 8];
                    f32x4 w0 = *(const f32x4*)&w3s[g_l3 * 32 + c4 * 8];
                    f32x4 w1v = *(const f32x4*)&w3s[g_l3 * 32 + c4 * 8 + 4];
                    acc = fmaf((float)v[0], w0[0], acc);
                    acc = fmaf((float)v[1], w0[1], acc);
                    acc = fmaf((float)v[2], w0[2], acc);
                    acc = fmaf((float)v[3], w0[3], acc);
                    acc = fmaf((float)v[4], w1v[0], acc);
                    acc = fmaf((float)v[5], w1v[1], acc);
                    acc = fmaf((float)v[6], w1v[2], acc);
                    acc = fmaf((float)v[7], w1v[3], acc);
                }
                outs[(long)g_l3 * BT + (long)(b0 + r_h) * TT + (ci << 4) + row] = acc;
            }
        }
        __syncthreads();  // the ONE vmcnt-draining barrier per chunk
    }
}

extern "C" void kernel_launch(void* const* d_in, const int* in_sizes, int n_in,
                              void* d_out, int out_size, void* d_ws, size_t ws_size,
                              hipStream_t stream) {
    (void)in_sizes; (void)n_in; (void)out_size; (void)d_ws; (void)ws_size;
    const float* x      = (const float*)d_in[0];
    const float* h_init = (const float*)d_in[1];
    const float* c_init = (const float*)d_in[2];
    const float* W_ih   = (const float*)d_in[3];
    const float* W_hh   = (const float*)d_in[4];
    const float* b_ih   = (const float*)d_in[5];
    const float* b_hh   = (const float*)d_in[6];
    const float* W1     = (const float*)d_in[7];
    const float* b1     = (const float*)d_in[8];
    const float* W2     = (const float*)d_in[9];
    const float* b2     = (const float*)d_in[10];
    const float* W3     = (const float*)d_in[11];
    const float* b3     = (const float*)d_in[12];
    float* y    = (float*)d_out;
    float* outs = y + Y_SIZE;

    lstm_fused_kernel<<<dim3(256), dim3(256), 0, stream>>>(
        x, h_init, c_init, W_ih, W_hh, b_ih, b_hh,
        W1, b1, W2, b2, W3, b3, y, outs);
}